// Round 8
// baseline (269.000 us; speedup 1.0000x reference)
//
#include <hip/hip_runtime.h>
#include <hip/hip_bf16.h>
#include <stdint.h>

// Problem constants
#define BQ 128    // batch
#define NJ 512    // input capsules j
#define DD 300    // input dim
#define NC 10     // num_capsule i
#define DC 64     // dim_capsule k
#define MM 640    // NC*DC
#define KP 320    // K padded (mult of 64)
#define RT 5      // routing iterations

typedef __attribute__((ext_vector_type(8))) short short8;
typedef __attribute__((ext_vector_type(4))) float f32x4;

__device__ inline float lo16(uint v) { return __uint_as_float(v << 16); }
__device__ inline float hi16(uint v) { return __uint_as_float(v & 0xffff0000u); }

// ---------------- cast kernels ----------------

__global__ void k_cast_x(const float* __restrict__ x, __hip_bfloat16* __restrict__ xb) {
    int g = blockIdx.x * 256 + threadIdx.x;      // 65536*40 groups
    int row = g / 40, cg2 = g - row * 40;
    const float* src = x + (size_t)row * DD + cg2 * 8;
    float4 a = make_float4(0.f, 0.f, 0.f, 0.f), b4 = a;
    if (cg2 < 37) { a = *(const float4*)src; b4 = *(const float4*)(src + 4); }
    else if (cg2 == 37) { a = *(const float4*)src; }
    union { ushort u[8]; uint4 v; } o;
    float f[8] = {a.x, a.y, a.z, a.w, b4.x, b4.y, b4.z, b4.w};
#pragma unroll
    for (int e = 0; e < 8; ++e) {
        __hip_bfloat16 hh = __float2bfloat16(f[e]);
        o.u[e] = *(ushort*)&hh;
    }
    *(uint4*)(xb + (size_t)row * KP + cg2 * 8) = o.v;
}

__global__ void k_cast_w(const float* __restrict__ w, __hip_bfloat16* __restrict__ wt) {
    int idx = blockIdx.x * 256 + threadIdx.x;
    int m = idx / KP, k = idx - m * KP;
    float v = (k < DD) ? w[(size_t)k * MM + m] : 0.f;
    wt[idx] = __float2bfloat16(v);
}

// ---------------- MFMA GEMM + non-atomic column-sum stripes ----------------

__global__ __launch_bounds__(256)
void k_gemm(const __hip_bfloat16* __restrict__ A,
            const __hip_bfloat16* __restrict__ Bt,
            __hip_bfloat16* __restrict__ C,
            float* __restrict__ psu) {             // psu[1024][640] colsum stripes
    __shared__ __align__(16) __hip_bfloat16 As[128 * 64];
    __shared__ __align__(16) __hip_bfloat16 Bs[128 * 64];

    const int L  = blockIdx.x;
    const int n0 = ((L >> 3) % 5) * 128;
    const int m0 = ((L / 40) * 8 + (L & 7)) * 128;
    const int t  = threadIdx.x;
    const int w  = t >> 6, lane = t & 63;
    const int wrow = (w >> 1) * 64, wcol = (w & 1) * 64;
    const int quad = lane >> 4, r = lane & 15;

    f32x4 acc[4][4] = {};

    const int srow = t >> 3;
    const int sl   = (t & 7) ^ (srow & 7);
    const __hip_bfloat16* ag = A  + (size_t)(m0 + srow) * KP + sl * 8;
    const __hip_bfloat16* bg = Bt + (size_t)(n0 + srow) * KP + sl * 8;

    for (int kt = 0; kt < KP / 64; ++kt) {
        __syncthreads();
#pragma unroll
        for (int s = 0; s < 4; ++s) {
            __builtin_amdgcn_global_load_lds(
                (const __attribute__((address_space(1))) void*)(ag + (size_t)s * 32 * KP + kt * 64),
                (__attribute__((address_space(3))) void*)(&As[s * 2048 + t * 8]), 16, 0, 0);
            __builtin_amdgcn_global_load_lds(
                (const __attribute__((address_space(1))) void*)(bg + (size_t)s * 32 * KP + kt * 64),
                (__attribute__((address_space(3))) void*)(&Bs[s * 2048 + t * 8]), 16, 0, 0);
        }
        __syncthreads();

#pragma unroll
        for (int hh = 0; hh < 2; ++hh) {
            short8 af[4], bf[4];
#pragma unroll
            for (int mi = 0; mi < 4; ++mi) {
                int rho = wrow + mi * 16 + r;
                int p = (hh * 4 + quad) ^ (rho & 7);
                af[mi] = *(const short8*)&As[rho * 64 + p * 8];
            }
#pragma unroll
            for (int ni = 0; ni < 4; ++ni) {
                int rho = wcol + ni * 16 + r;
                int p = (hh * 4 + quad) ^ (rho & 7);
                bf[ni] = *(const short8*)&Bs[rho * 64 + p * 8];
            }
#pragma unroll
            for (int mi = 0; mi < 4; ++mi)
#pragma unroll
                for (int ni = 0; ni < 4; ++ni)
                    acc[mi][ni] = __builtin_amdgcn_mfma_f32_16x16x32_bf16(
                        af[mi], bf[ni], acc[mi][ni], 0, 0, 0);
        }
    }

#pragma unroll
    for (int mi = 0; mi < 4; ++mi)
#pragma unroll
        for (int ni = 0; ni < 4; ++ni) {
            int col = n0 + wcol + ni * 16 + r;
#pragma unroll
            for (int p = 0; p < 4; ++p) {
                int row = m0 + wrow + mi * 16 + quad * 4 + p;
                C[(size_t)row * MM + col] = __float2bfloat16(acc[mi][ni][p]);
            }
        }

    // column-sum stripe: fold 16 rows in-reg, butterfly over quad, plain store.
    // psu row = (m0/128)*2 + wrow/64; each (wave,ni,r) column written once.
    float cs[4];
#pragma unroll
    for (int ni = 0; ni < 4; ++ni) {
        float s = 0.f;
#pragma unroll
        for (int mi = 0; mi < 4; ++mi)
#pragma unroll
            for (int p = 0; p < 4; ++p) s += acc[mi][ni][p];
        s += __shfl_xor(s, 16, 64);
        s += __shfl_xor(s, 32, 64);
        cs[ni] = s;
    }
    if (quad == 0) {
        int mb2 = (m0 >> 6) + (wrow >> 6);
#pragma unroll
        for (int ni = 0; ni < 4; ++ni)
            psu[(size_t)mb2 * MM + n0 + wcol + ni * 16 + r] = cs[ni];
    }
}

// ---------------- fused routing pass (TJ=32, 4 k/thread) ----------------
// Block = (b, quarter q), 512 threads, 4 tiles of 32 j (40960 B contiguous).
// Thread: jd = t>>4 (j in tile), kg = t&15 (4 k). k-reduce width 16 (was 32):
// red transpose halves; uv reads are b64 (2x bytes/op); outl stored bf16.
// squash(lambda*v) == squash(v), so no 0.1 scale anywhere.

#define TJ 32
#define NT 4
#define TILE_BYTES (TJ * MM * 2)   // 40960

__global__ __launch_bounds__(512, 2)
void k_pass(const __hip_bfloat16* __restrict__ u, const float* __restrict__ pprev,
            float* __restrict__ pnext, int nch) {
    // smem: ub 40960 | red 16*321*4=20544 | blj 1280 | outl(bf16) 1280 = 64064
    __shared__ __align__(16) char smem[TILE_BYTES + 16 * 321 * 4 + 320 * 4 + MM * 2];
    ushort* ub    = (ushort*)smem;                          // [32][640] bf16 tile
    float*  red   = (float*)(smem + TILE_BYTES);            // [16][321] padded
    float*  blj   = (float*)(smem + TILE_BYTES + 20544);    // [320] = [jd][i]
    ushort* outl  = (ushort*)(smem + TILE_BYTES + 20544 + 1280); // [640] bf16
    float*  pored = (float*)smem;                           // [8][648] epilogue reuse

    const int t   = threadIdx.x;
    const int blk = blockIdx.x;
    const int b   = blk >> 2, q = blk & 3;
    const int w   = t >> 6, lane = t & 63;
    const int jd  = t >> 4, kg = t & 15;

    const char* ubase = (const char*)(u + (size_t)(b * NJ + q * 128) * MM);

    // preload tile 0: 5 fully-coalesced 8192 B slabs
    uint4 s0 = *(const uint4*)(ubase + 0 * 8192 + t * 16);
    uint4 s1 = *(const uint4*)(ubase + 1 * 8192 + t * 16);
    uint4 s2 = *(const uint4*)(ubase + 2 * 8192 + t * 16);
    uint4 s3 = *(const uint4*)(ubase + 3 * 8192 + t * 16);
    uint4 s4 = *(const uint4*)(ubase + 4 * 8192 + t * 16);

    // prologue: outl = squash(sum of nch chunks), bf16; waves 0..4, two i each
    if (w < 5) {
        int i0 = w * 64 + lane, i1 = 320 + i0;
        float a0 = 0.f, a1 = 0.f;
        for (int qq = 0; qq < nch; ++qq) {
            a0 += pprev[(size_t)(b * nch + qq) * MM + i0];
            a1 += pprev[(size_t)(b * nch + qq) * MM + i1];
        }
        float q0 = a0 * a0, q1 = a1 * a1;
#pragma unroll
        for (int m = 32; m >= 1; m >>= 1) {
            q0 += __shfl_xor(q0, m, 64);
            q1 += __shfl_xor(q1, m, 64);
        }
        __hip_bfloat16 h0 = __float2bfloat16(a0 * rsqrtf(q0 + 1e-7f));
        __hip_bfloat16 h1 = __float2bfloat16(a1 * rsqrtf(q1 + 1e-7f));
        outl[i0] = *(ushort*)&h0;
        outl[i1] = *(ushort*)&h1;
    }

    float po[40];
#pragma unroll
    for (int e = 0; e < 40; ++e) po[e] = 0.f;

    for (int tt = 0; tt < NT; ++tt) {
        uint4 n0v, n1v, n2v, n3v, n4v;
        if (tt + 1 < NT) {                        // next tile's loads in flight
            const char* ns = ubase + (size_t)(tt + 1) * TILE_BYTES;
            n0v = *(const uint4*)(ns + 0 * 8192 + t * 16);
            n1v = *(const uint4*)(ns + 1 * 8192 + t * 16);
            n2v = *(const uint4*)(ns + 2 * 8192 + t * 16);
            n3v = *(const uint4*)(ns + 3 * 8192 + t * 16);
            n4v = *(const uint4*)(ns + 4 * 8192 + t * 16);
        }
        __syncthreads();                          // prev compute done (+outl on tt=0)
        *(uint4*)((char*)ub + 0 * 8192 + t * 16) = s0;
        *(uint4*)((char*)ub + 1 * 8192 + t * 16) = s1;
        *(uint4*)((char*)ub + 2 * 8192 + t * 16) = s2;
        *(uint4*)((char*)ub + 3 * 8192 + t * 16) = s3;
        *(uint4*)((char*)ub + 4 * 8192 + t * 16) = s4;
        __syncthreads();                          // tile visible

        const ushort* urow = ub + jd * MM;
        uint2 uv[10];
#pragma unroll
        for (int i = 0; i < 10; ++i) {
            uv[i] = *(const uint2*)(urow + i * 64 + kg * 4);          // b64, BW floor
            uint2 ov = *(const uint2*)(outl + i * 64 + kg * 4);       // b64 broadcast
            float pb = lo16(uv[i].x) * lo16(ov.x) + hi16(uv[i].x) * hi16(ov.x)
                     + lo16(uv[i].y) * lo16(ov.y) + hi16(uv[i].y) * hi16(ov.y);
            red[kg * 321 + jd * 10 + i] = pb;     // banks (kg+10jd+i)%32: <=2-way
        }
        __syncthreads();
        if (t < 320) {                            // t = jd*10 + i
            float ss = 0.f;
#pragma unroll
            for (int g = 0; g < 16; ++g) ss += red[g * 321 + t];
            blj[t] = ss;
        }
        __syncthreads();
        float c[10];
        {
            float bl[10], mx = -1e30f;
#pragma unroll
            for (int i = 0; i < 10; ++i) { bl[i] = blj[jd * 10 + i]; mx = fmaxf(mx, bl[i]); }
            float ssum = 0.f;
#pragma unroll
            for (int i = 0; i < 10; ++i) { bl[i] = __expf(bl[i] - mx); ssum += bl[i]; }
            float inv = 1.f / ssum;
#pragma unroll
            for (int i = 0; i < 10; ++i) c[i] = bl[i] * inv;
        }
#pragma unroll
        for (int i = 0; i < 10; ++i) {
            po[i * 4 + 0] += c[i] * lo16(uv[i].x);
            po[i * 4 + 1] += c[i] * hi16(uv[i].x);
            po[i * 4 + 2] += c[i] * lo16(uv[i].y);
            po[i * 4 + 3] += c[i] * hi16(uv[i].y);
        }
        s0 = n0v; s1 = n1v; s2 = n2v; s3 = n3v; s4 = n4v;
    }

    // epilogue: butterfly over the wave's 4 jd values, LDS transpose over 8 waves
#pragma unroll
    for (int e = 0; e < 40; ++e) {
        po[e] += __shfl_xor(po[e], 16, 64);
        po[e] += __shfl_xor(po[e], 32, 64);
    }
    __syncthreads();                              // ub dead -> pored [8][648]
    if ((lane >> 4) == 0) {                       // lanes 0..15 = kg
#pragma unroll
        for (int i = 0; i < 10; ++i) {
            f32x4 v = {po[i * 4 + 0], po[i * 4 + 1], po[i * 4 + 2], po[i * 4 + 3]};
            *(f32x4*)&pored[w * 648 + i * 64 + kg * 4] = v;
        }
    }
    __syncthreads();
    for (int m = t; m < MM; m += 512) {
        float ss = 0.f;
#pragma unroll
        for (int ww = 0; ww < 8; ++ww) ss += pored[ww * 648 + m];
        pnext[(size_t)blk * MM + m] = ss;
    }
}

// final squash: sum the 4 per-quarter partials, normalize each (b,i) 64-vector
__global__ __launch_bounds__(640)
void k_squash(const float* __restrict__ pbuf, float* __restrict__ dst) {
    int b = blockIdx.x, t = threadIdx.x;     // t = i*64 + k; wave = i
    float s = 0.f;
#pragma unroll
    for (int qq = 0; qq < 4; ++qq) s += pbuf[(size_t)(b * 4 + qq) * MM + t];
    float sq = s * s;
#pragma unroll
    for (int m = 32; m >= 1; m >>= 1) sq += __shfl_xor(sq, m, 64);
    dst[(size_t)b * MM + t] = s * rsqrtf(sq + 1e-7f);
}

// ---------------- launch ----------------

extern "C" void kernel_launch(void* const* d_in, const int* in_sizes, int n_in,
                              void* d_out, int out_size, void* d_ws, size_t ws_size,
                              hipStream_t stream) {
    const float* x = (const float*)d_in[0];   // [128,512,300]
    const float* W = (const float*)d_in[1];   // [1,300,640]
    float* out = (float*)d_out;               // [128,10,64]

    char* ws = (char*)d_ws;
    size_t o = 0;
    __hip_bfloat16* xb = (__hip_bfloat16*)(ws + o); o += (size_t)BQ * NJ * KP * 2;  // 41.9 MB
    __hip_bfloat16* wt = (__hip_bfloat16*)(ws + o); o += (size_t)MM * KP * 2;       // 0.4 MB
    __hip_bfloat16* u  = (__hip_bfloat16*)(ws + o); o += (size_t)BQ * NJ * MM * 2;  // 83.9 MB
    float* pb0 = (float*)(ws + o); o += (size_t)512 * MM * 4;                       // 1.3 MB
    float* pb1 = (float*)(ws + o); o += (size_t)512 * MM * 4;                       // 1.3 MB
    float* psu = (float*)(ws + o); o += (size_t)1024 * MM * 4;                      // 2.6 MB

    k_cast_x<<<(BQ * NJ * 40) / 256, 256, 0, stream>>>(x, xb);
    k_cast_w<<<(MM * KP) / 256, 256, 0, stream>>>(W, wt);
    k_gemm<<<2560, 256, 0, stream>>>(xb, wt, u, psu);

    // iterations 1..4 (iteration 0 lives in the GEMM colsum stripes)
    k_pass<<<512, 512, 0, stream>>>(u, psu, pb0, 8);
    k_pass<<<512, 512, 0, stream>>>(u, pb0, pb1, 4);
    k_pass<<<512, 512, 0, stream>>>(u, pb1, pb0, 4);
    k_pass<<<512, 512, 0, stream>>>(u, pb0, pb1, 4);
    k_squash<<<BQ, 640, 0, stream>>>(pb1, out);
}

// Round 9
// 250.064 us; speedup vs baseline: 1.0757x; 1.0757x over previous
//
#include <hip/hip_runtime.h>
#include <hip/hip_bf16.h>
#include <stdint.h>

// Problem constants
#define BQ 128    // batch
#define NJ 512    // input capsules j
#define DD 300    // input dim
#define NC 10     // num_capsule i
#define DC 64     // dim_capsule k
#define MM 640    // NC*DC
#define KP 320    // K padded (mult of 64)
#define RT 5      // routing iterations

typedef __attribute__((ext_vector_type(8))) short short8;
typedef __attribute__((ext_vector_type(4))) float f32x4;

// ---------------- cast kernels ----------------

__global__ void k_cast_x(const float* __restrict__ x, __hip_bfloat16* __restrict__ xb) {
    int g = blockIdx.x * 256 + threadIdx.x;      // 65536*40 groups
    int row = g / 40, cg2 = g - row * 40;
    const float* src = x + (size_t)row * DD + cg2 * 8;
    float4 a = make_float4(0.f, 0.f, 0.f, 0.f), b4 = a;
    if (cg2 < 37) { a = *(const float4*)src; b4 = *(const float4*)(src + 4); }
    else if (cg2 == 37) { a = *(const float4*)src; }
    union { ushort u[8]; uint4 v; } o;
    float f[8] = {a.x, a.y, a.z, a.w, b4.x, b4.y, b4.z, b4.w};
#pragma unroll
    for (int e = 0; e < 8; ++e) {
        __hip_bfloat16 hh = __float2bfloat16(f[e]);
        o.u[e] = *(ushort*)&hh;
    }
    *(uint4*)(xb + (size_t)row * KP + cg2 * 8) = o.v;
}

__global__ void k_cast_w(const float* __restrict__ w, __hip_bfloat16* __restrict__ wt) {
    int idx = blockIdx.x * 256 + threadIdx.x;
    int m = idx / KP, k = idx - m * KP;
    float v = (k < DD) ? w[(size_t)k * MM + m] : 0.f;
    wt[idx] = __float2bfloat16(v);
}

// ---------------- MFMA GEMM + non-atomic column-sum stripes ----------------

__global__ __launch_bounds__(256)
void k_gemm(const __hip_bfloat16* __restrict__ A,
            const __hip_bfloat16* __restrict__ Bt,
            __hip_bfloat16* __restrict__ C,
            float* __restrict__ psu) {             // psu[1024][640] colsum stripes
    __shared__ __align__(16) __hip_bfloat16 As[128 * 64];
    __shared__ __align__(16) __hip_bfloat16 Bs[128 * 64];

    const int L  = blockIdx.x;
    const int n0 = ((L >> 3) % 5) * 128;
    const int m0 = ((L / 40) * 8 + (L & 7)) * 128;
    const int t  = threadIdx.x;
    const int w  = t >> 6, lane = t & 63;
    const int wrow = (w >> 1) * 64, wcol = (w & 1) * 64;
    const int quad = lane >> 4, r = lane & 15;

    f32x4 acc[4][4] = {};

    const int srow = t >> 3;
    const int sl   = (t & 7) ^ (srow & 7);
    const __hip_bfloat16* ag = A  + (size_t)(m0 + srow) * KP + sl * 8;
    const __hip_bfloat16* bg = Bt + (size_t)(n0 + srow) * KP + sl * 8;

    for (int kt = 0; kt < KP / 64; ++kt) {
        __syncthreads();
#pragma unroll
        for (int s = 0; s < 4; ++s) {
            __builtin_amdgcn_global_load_lds(
                (const __attribute__((address_space(1))) void*)(ag + (size_t)s * 32 * KP + kt * 64),
                (__attribute__((address_space(3))) void*)(&As[s * 2048 + t * 8]), 16, 0, 0);
            __builtin_amdgcn_global_load_lds(
                (const __attribute__((address_space(1))) void*)(bg + (size_t)s * 32 * KP + kt * 64),
                (__attribute__((address_space(3))) void*)(&Bs[s * 2048 + t * 8]), 16, 0, 0);
        }
        __syncthreads();

#pragma unroll
        for (int hh = 0; hh < 2; ++hh) {
            short8 af[4], bf[4];
#pragma unroll
            for (int mi = 0; mi < 4; ++mi) {
                int rho = wrow + mi * 16 + r;
                int p = (hh * 4 + quad) ^ (rho & 7);
                af[mi] = *(const short8*)&As[rho * 64 + p * 8];
            }
#pragma unroll
            for (int ni = 0; ni < 4; ++ni) {
                int rho = wcol + ni * 16 + r;
                int p = (hh * 4 + quad) ^ (rho & 7);
                bf[ni] = *(const short8*)&Bs[rho * 64 + p * 8];
            }
#pragma unroll
            for (int mi = 0; mi < 4; ++mi)
#pragma unroll
                for (int ni = 0; ni < 4; ++ni)
                    acc[mi][ni] = __builtin_amdgcn_mfma_f32_16x16x32_bf16(
                        af[mi], bf[ni], acc[mi][ni], 0, 0, 0);
        }
    }

#pragma unroll
    for (int mi = 0; mi < 4; ++mi)
#pragma unroll
        for (int ni = 0; ni < 4; ++ni) {
            int col = n0 + wcol + ni * 16 + r;
#pragma unroll
            for (int p = 0; p < 4; ++p) {
                int row = m0 + wrow + mi * 16 + quad * 4 + p;
                C[(size_t)row * MM + col] = __float2bfloat16(acc[mi][ni][p]);
            }
        }

    // column-sum stripe: fold 16 rows in-reg, butterfly over quad, plain store.
    // stripe row mb2 = (m0/64) + wrow/64; each (stripe, col) written exactly once.
    float cs[4];
#pragma unroll
    for (int ni = 0; ni < 4; ++ni) {
        float s = 0.f;
#pragma unroll
        for (int mi = 0; mi < 4; ++mi)
#pragma unroll
            for (int p = 0; p < 4; ++p) s += acc[mi][ni][p];
        s += __shfl_xor(s, 16, 64);
        s += __shfl_xor(s, 32, 64);
        cs[ni] = s;
    }
    if (quad == 0) {
        int mb2 = (m0 >> 6) + (wrow >> 6);
#pragma unroll
        for (int ni = 0; ni < 4; ++ni)
            psu[(size_t)mb2 * MM + n0 + wcol + ni * 16 + r] = cs[ni];
    }
}

// ---------------- fused routing pass (EXACT round-7 inner loop) ----------------
// Block = (b, quarter q). 512 threads, 8 tiles of TJ=16 j, register->LDS pipelined
// staging. Prologue: squash(sum of nch prev chunks) — nch=8 stripes from gemm on
// the first pass (squash is scale-invariant so the 1/10 factor drops), else 4.

#define TJ 16
#define NT 8
#define TILE_BYTES (TJ * MM * 2)   // 20480

__global__ __launch_bounds__(512)
void k_pass(const __hip_bfloat16* __restrict__ u, const float* __restrict__ pprev,
            float* __restrict__ pnext, int nch) {
    // smem: ub 20480 | red 32*161*4=20608 | blj 640 | outl 2560   (44288 B)
    __shared__ __align__(16) char smem[TILE_BYTES + 32 * 161 * 4 + 160 * 4 + MM * 4];
    ushort* ub    = (ushort*)smem;                          // [16][640] bf16 tile
    float*  red   = (float*)(smem + TILE_BYTES);            // [32][161] padded
    float*  blj   = (float*)(smem + TILE_BYTES + 20608);    // [160] = [jd][i]
    float*  outl  = (float*)(smem + TILE_BYTES + 20608 + 640); // [640] out_prev
    float*  pored = (float*)smem;                           // epilogue reuse

    const int t   = threadIdx.x;
    const int blk = blockIdx.x;
    const int b   = blk >> 2, q = blk & 3;
    const int w   = t >> 6, lane = t & 63;
    const int jd  = t >> 5, kg = t & 31;

    const char* ubase = (const char*)(u + (size_t)(b * NJ + q * 128) * MM);

    // preload tile 0 (in flight during prologue)
    uint4 sa = *(const uint4*)(ubase + t * 16);
    uint4 sb = *(const uint4*)(ubase + 8192 + t * 16);
    uint2 sc = *(const uint2*)(ubase + 16384 + t * 8);

    // prologue: outl = squash(sum of nch chunks); waves 0..4, two i each
    if (w < 5) {
        int i0 = w * 64 + lane, i1 = 320 + i0;
        float s0 = 0.f, s1 = 0.f;
        for (int qq = 0; qq < nch; ++qq) {
            s0 += pprev[(size_t)(b * nch + qq) * MM + i0];
            s1 += pprev[(size_t)(b * nch + qq) * MM + i1];
        }
        float q0 = s0 * s0, q1 = s1 * s1;
#pragma unroll
        for (int m = 32; m >= 1; m >>= 1) {
            q0 += __shfl_xor(q0, m, 64);
            q1 += __shfl_xor(q1, m, 64);
        }
        outl[i0] = s0 * rsqrtf(q0 + 1e-7f);
        outl[i1] = s1 * rsqrtf(q1 + 1e-7f);
    }

    float po[20];
#pragma unroll
    for (int e = 0; e < 20; ++e) po[e] = 0.f;

    for (int tt = 0; tt < NT; ++tt) {
        uint4 na, nb; uint2 nc2;
        if (tt + 1 < NT) {                        // next tile's loads in flight
            const char* ns = ubase + (size_t)(tt + 1) * TILE_BYTES;
            na  = *(const uint4*)(ns + t * 16);
            nb  = *(const uint4*)(ns + 8192 + t * 16);
            nc2 = *(const uint2*)(ns + 16384 + t * 8);
        }
        __syncthreads();                          // prev tile compute done (outl visible too)
        *(uint4*)((char*)ub + t * 16)        = sa;
        *(uint4*)((char*)ub + 8192 + t * 16) = sb;
        *(uint2*)((char*)ub + 16384 + t * 8) = sc;
        __syncthreads();                          // tile visible

        const ushort* urow = ub + jd * MM;
        uint uv[10];
#pragma unroll
        for (int i = 0; i < 10; ++i)
            uv[i] = *(const uint*)(urow + i * 64 + kg * 2);   // 2-way alias, free

        // bl partial: dot with outl from LDS
#pragma unroll
        for (int i = 0; i < 10; ++i) {
            float u0 = __uint_as_float(uv[i] << 16);
            float u1 = __uint_as_float(uv[i] & 0xffff0000u);
            float2 oo = *(const float2*)(outl + i * 64 + kg * 2);
            red[kg * 161 + jd * 10 + i] = u0 * oo.x + u1 * oo.y;
        }
        __syncthreads();
        if (t < 160) {                            // t = jd*10 + i
            float s = 0.f;
#pragma unroll
            for (int g = 0; g < 32; ++g) s += red[g * 161 + t];
            blj[t] = s;
        }
        __syncthreads();
        float c[10];
        {
            float bl[10], mx = -1e30f;
#pragma unroll
            for (int i = 0; i < 10; ++i) { bl[i] = blj[jd * 10 + i]; mx = fmaxf(mx, bl[i]); }
            float ssum = 0.f;
#pragma unroll
            for (int i = 0; i < 10; ++i) { bl[i] = __expf(bl[i] - mx); ssum += bl[i]; }
            float inv = 1.f / ssum;
#pragma unroll
            for (int i = 0; i < 10; ++i) c[i] = bl[i] * inv;
        }
#pragma unroll
        for (int i = 0; i < 10; ++i) {
            float u0 = __uint_as_float(uv[i] << 16);
            float u1 = __uint_as_float(uv[i] & 0xffff0000u);
            po[i * 2 + 0] += c[i] * u0;
            po[i * 2 + 1] += c[i] * u1;
        }
        sa = na; sb = nb; sc = nc2;
    }

    // epilogue: fold jd-halves in-register, then LDS transpose over 8 waves
#pragma unroll
    for (int e = 0; e < 20; ++e) po[e] += __shfl_xor(po[e], 32, 64);
    __syncthreads();                              // ub dead -> pored
    if ((t & 63) < 32) {
#pragma unroll
        for (int e = 0; e < 20; ++e) pored[(w * 32 + kg) * 20 + e] = po[e];
    }
    __syncthreads();
    for (int m = t; m < MM; m += 512) {
        int i = m >> 6, k = m & 63, kg2 = k >> 1, kd = k & 1;
        float s = 0.f;
#pragma unroll
        for (int ww = 0; ww < 8; ++ww) s += pored[(ww * 32 + kg2) * 20 + i * 2 + kd];
        pnext[(size_t)blk * MM + m] = s;
    }
}

// final squash: sum the 4 per-quarter partials, normalize each (b,i) 64-vector
__global__ __launch_bounds__(640)
void k_squash(const float* __restrict__ pbuf, float* __restrict__ dst) {
    int b = blockIdx.x, t = threadIdx.x;     // t = i*64 + k; wave = i
    float s = 0.f;
#pragma unroll
    for (int qq = 0; qq < 4; ++qq) s += pbuf[(size_t)(b * 4 + qq) * MM + t];
    float sq = s * s;
#pragma unroll
    for (int m = 32; m >= 1; m >>= 1) sq += __shfl_xor(sq, m, 64);
    dst[(size_t)b * MM + t] = s * rsqrtf(sq + 1e-7f);
}

// ---------------- launch ----------------

extern "C" void kernel_launch(void* const* d_in, const int* in_sizes, int n_in,
                              void* d_out, int out_size, void* d_ws, size_t ws_size,
                              hipStream_t stream) {
    const float* x = (const float*)d_in[0];   // [128,512,300]
    const float* W = (const float*)d_in[1];   // [1,300,640]
    float* out = (float*)d_out;               // [128,10,64]

    char* ws = (char*)d_ws;
    size_t o = 0;
    __hip_bfloat16* xb = (__hip_bfloat16*)(ws + o); o += (size_t)BQ * NJ * KP * 2;  // 41.9 MB
    __hip_bfloat16* wt = (__hip_bfloat16*)(ws + o); o += (size_t)MM * KP * 2;       // 0.4 MB
    __hip_bfloat16* u  = (__hip_bfloat16*)(ws + o); o += (size_t)BQ * NJ * MM * 2;  // 83.9 MB
    float* pb0 = (float*)(ws + o); o += (size_t)512 * MM * 4;                       // 1.3 MB
    float* pb1 = (float*)(ws + o); o += (size_t)512 * MM * 4;                       // 1.3 MB
    float* psu = (float*)(ws + o); o += (size_t)1024 * MM * 4;                      // 2.6 MB

    k_cast_x<<<(BQ * NJ * 40) / 256, 256, 0, stream>>>(x, xb);
    k_cast_w<<<(MM * KP) / 256, 256, 0, stream>>>(W, wt);
    k_gemm<<<2560, 256, 0, stream>>>(xb, wt, u, psu);

    // iterations 1..4 (iteration 0 lives in the GEMM colsum stripes)
    k_pass<<<512, 512, 0, stream>>>(u, psu, pb0, 8);
    k_pass<<<512, 512, 0, stream>>>(u, pb0, pb1, 4);
    k_pass<<<512, 512, 0, stream>>>(u, pb1, pb0, 4);
    k_pass<<<512, 512, 0, stream>>>(u, pb0, pb1, 4);
    k_squash<<<BQ, 640, 0, stream>>>(pb1, out);
}